// Round 11
// baseline (198.881 us; speedup 1.0000x reference)
//
#include <hip/hip_runtime.h>

#define NEG_SLOPE 0.2f
#define LRELU(x) ((x) > 0.0f ? (x) : NEG_SLOPE * (x))

typedef short short8 __attribute__((ext_vector_type(8)));
typedef unsigned short ushort8 __attribute__((ext_vector_type(8)));
typedef float f32x4v __attribute__((ext_vector_type(4)));

__device__ __forceinline__ unsigned short f2bf(float f) {
  unsigned int u = __float_as_uint(f);
  unsigned int r = (u + 0x7FFFu + ((u >> 16) & 1u)) >> 16;
  return (unsigned short)r;
}

__device__ __forceinline__ float bf2f(unsigned short u) {
  return __uint_as_float(((unsigned int)u) << 16);
}

__device__ __forceinline__ unsigned int cvt_pk_bf16(float lo, float hi) {
  unsigned int r;
  asm("v_cvt_pk_bf16_f32 %0, %1, %2" : "=v"(r) : "v"(lo), "v"(hi));
  return r;
}

__device__ __forceinline__ void gload_lds16(const void* g, void* l) {
  __builtin_amdgcn_global_load_lds(
      (const __attribute__((address_space(1))) unsigned int*)g,
      (__attribute__((address_space(3))) unsigned int*)l, 16, 0, 0);
}

// block-range split constants
#define CBC 448    // count blocks (fused_pre)
#define CBW 64     // convert_wt blocks (fused_pre)
#define CBF 1024   // fill blocks (fused_main, scheduled FIRST)

// ---- K1: count || convert_wt ------------------------------------------------
__global__ __launch_bounds__(256) void fused_pre(
    const float* __restrict__ W, unsigned short* __restrict__ Wtb,
    const int* __restrict__ ei, int* __restrict__ deg, int E) {
  int b = blockIdx.x;
  int tid = threadIdx.x;
  if (b < CBC) {
    for (int e = b * 256 + tid; e < E; e += CBC * 256)
      atomicAdd(&deg[ei[E + e]], 1);
  } else {
    int bb = b - CBC;
    for (int idx = bb * 256 + tid; idx < 256 * 256; idx += CBW * 256) {
      int n = idx >> 8, k = idx & 255;
      Wtb[n * 256 + k] = f2bf(W[k * 256 + n]);
    }
  }
}

// ------------------------------- scan ----------------------------------------
__global__ __launch_bounds__(1024) void scan1_kernel(const int* __restrict__ deg,
                                                     int* __restrict__ row_start,
                                                     int* __restrict__ bsum, int N) {
  __shared__ int buf[1024];
  int i = blockIdx.x * 1024 + (int)threadIdx.x;
  int v = (i < N) ? deg[i] : 0;
  buf[threadIdx.x] = v;
  __syncthreads();
  int run = v;
  for (int off = 1; off < 1024; off <<= 1) {
    int t = ((int)threadIdx.x >= off) ? buf[threadIdx.x - off] : 0;
    __syncthreads();
    run += t;
    buf[threadIdx.x] = run;
    __syncthreads();
  }
  if (i < N) row_start[i] = run - v;  // exclusive, pre-block-offset
  if (threadIdx.x == 1023) bsum[blockIdx.x] = run;
}

// adds block offset; also seeds next[] (the fill's slot allocator)
__global__ __launch_bounds__(1024) void scan_off(int* __restrict__ row_start,
                                                 int* __restrict__ next,
                                                 const int* __restrict__ bsum,
                                                 int nb, int N) {
  __shared__ int s_off;
  int b = blockIdx.x;
  if (threadIdx.x < 64) {
    int acc = 0;
    for (int j = (int)threadIdx.x; j < b; j += 64) acc += bsum[j];
    for (int off = 32; off; off >>= 1) acc += __shfl_down(acc, off, 64);
    if (threadIdx.x == 0) s_off = acc;
  }
  __syncthreads();
  int off = s_off;
  int i = b * 1024 + (int)threadIdx.x;
  if (i < N) {
    int v = row_start[i] + off;
    row_start[i] = v;
    next[i] = v;
  }
  if (b == nb - 1 && threadIdx.x == 0) row_start[N] = off + bsum[b];
}

// ---- K4: CSR fill (bid<CBF, scheduled first) || MFMA GEMM -------------------
// fill: slot = atomicAdd(&next[d],1)  (no row_start gather).
// gemm: 128x128 tile, reg-staged f32 A -> cvt_pk -> bf16 LDS; B via gload_lds.
// XCD-paired mapping requires m-block count % 8 == 0 (launcher pads Mp to 1024
// rows): blocks gb and gb+8 share A rows -> same XCD L2 (round-robin dispatch).
__global__ __launch_bounds__(256) void fused_main(
    const float* __restrict__ Xf, const unsigned short* __restrict__ Wtb,
    const float* __restrict__ attS, const float* __restrict__ attD,
    unsigned short* __restrict__ XHb, float* __restrict__ a_src,
    float* __restrict__ a_dst,
    const int* __restrict__ ei, int* __restrict__ next,
    int* __restrict__ csr_src, int E, int N) {
  __shared__ unsigned short lA[128 * 32];  // 8KB [row][k], 64B/row
  __shared__ unsigned short lB[128 * 32];  // 8KB [n][k],   64B/row
  const int bid = blockIdx.x;
  const int tid = threadIdx.x;

  if (bid < CBF) {
    // ---------------- fill (runs first, overlaps gemm) ----------------
    for (int e = bid * 256 + tid; e < E; e += CBF * 256) {
      int d = ei[E + e];
      int slot = atomicAdd(&next[d], 1);
      csr_src[slot] = ei[e];
    }
    return;
  }

  // ---------------- gemm ----------------
  const int gb = bid - CBF;
  const int lane = tid & 63;
  const int wave = tid >> 6;
  const int m0 = ((gb >> 4) * 8 + (gb & 7)) * 128;
  const int n0 = ((gb >> 3) & 1) * 128;
  const int wr = (wave >> 1) * 64;
  const int wc = (wave & 1) * 64;

  f32x4v acc[4][4];
#pragma unroll
  for (int i = 0; i < 4; ++i)
#pragma unroll
    for (int j = 0; j < 4; ++j) acc[i][j] = (f32x4v)(0.0f);

  const int srow = tid >> 2;
  const int skb = (tid & 3) * 16;
  const float* ap0 = Xf + (size_t)min(m0 + (tid >> 2), N - 1) * 256 + (tid & 3) * 8;
  const float* ap1 = Xf + (size_t)min(m0 + 64 + (tid >> 2), N - 1) * 256 + (tid & 3) * 8;

  const char* WtC = (const char*)Wtb;
  char* lAc = (char*)&lA[0];
  char* lBc = (char*)&lB[0];
  const int ldsB0 = wave * 1024;
  const int lr = lane & 15;
  const int hq = lane >> 4;
  const int kq = hq * 16;

  float4 c0 = *reinterpret_cast<const float4*>(ap0);
  float4 c1 = *reinterpret_cast<const float4*>(ap0 + 4);
  float4 c2 = *reinterpret_cast<const float4*>(ap1);
  float4 c3 = *reinterpret_cast<const float4*>(ap1 + 4);

#pragma unroll
  for (int kk = 0; kk < 8; ++kk) {
    const int k0 = kk * 32;
    gload_lds16(WtC + (size_t)(n0 + srow) * 512 + (size_t)k0 * 2 + skb, lBc + ldsB0);
    gload_lds16(WtC + (size_t)(n0 + srow + 64) * 512 + (size_t)k0 * 2 + skb,
                lBc + ldsB0 + 4096);
    {
      uint4 w0, w1;
      w0.x = cvt_pk_bf16(c0.x, c0.y); w0.y = cvt_pk_bf16(c0.z, c0.w);
      w0.z = cvt_pk_bf16(c1.x, c1.y); w0.w = cvt_pk_bf16(c1.z, c1.w);
      w1.x = cvt_pk_bf16(c2.x, c2.y); w1.y = cvt_pk_bf16(c2.z, c2.w);
      w1.z = cvt_pk_bf16(c3.x, c3.y); w1.w = cvt_pk_bf16(c3.z, c3.w);
      *reinterpret_cast<uint4*>(lAc + tid * 16) = w0;          // rows 0..63
      *reinterpret_cast<uint4*>(lAc + 4096 + tid * 16) = w1;   // rows 64..127
    }
    if (kk < 7) {
      c0 = *reinterpret_cast<const float4*>(ap0 + k0 + 32);
      c1 = *reinterpret_cast<const float4*>(ap0 + k0 + 36);
      c2 = *reinterpret_cast<const float4*>(ap1 + k0 + 32);
      c3 = *reinterpret_cast<const float4*>(ap1 + k0 + 36);
    }
    __syncthreads();

    short8 a[4], b[4];
#pragma unroll
    for (int i = 0; i < 4; ++i)
      a[i] = *reinterpret_cast<const short8*>(lAc + (wr + i * 16 + lr) * 64 + kq);
#pragma unroll
    for (int j = 0; j < 4; ++j)
      b[j] = *reinterpret_cast<const short8*>(lBc + (wc + j * 16 + lr) * 64 + kq);
#pragma unroll
    for (int i = 0; i < 4; ++i)
#pragma unroll
      for (int j = 0; j < 4; ++j)
        acc[i][j] = __builtin_amdgcn_mfma_f32_16x16x32_bf16(a[i], b[j], acc[i][j], 0, 0, 0);
    __syncthreads();
  }

  // ---- epilogue: fused attention dots + bf16 store ----
  const int h = (n0 + wc) >> 6;
  float ws_[4], wd_[4];
#pragma unroll
  for (int j = 0; j < 4; ++j) {
    ws_[j] = attS[h * 64 + j * 16 + lr];
    wd_[j] = attD[h * 64 + j * 16 + lr];
  }
  const int rbase = m0 + wr + hq * 4;

#pragma unroll
  for (int i = 0; i < 4; ++i) {
#pragma unroll
    for (int r = 0; r < 4; ++r) {
      float ps = 0.f, pd = 0.f;
#pragma unroll
      for (int j = 0; j < 4; ++j) {
        ps += acc[i][j][r] * ws_[j];
        pd += acc[i][j][r] * wd_[j];
      }
#pragma unroll
      for (int off = 1; off < 16; off <<= 1) {
        ps += __shfl_xor(ps, off, 64);
        pd += __shfl_xor(pd, off, 64);
      }
      int row = rbase + i * 16 + r;
      if (lr == 0 && row < N) {
        a_src[row * 4 + h] = ps;
        a_dst[row * 4 + h] = pd;
      }
    }
  }

#pragma unroll
  for (int i = 0; i < 4; ++i)
#pragma unroll
    for (int j = 0; j < 4; ++j) {
      int col = n0 + wc + j * 16 + lr;
#pragma unroll
      for (int r = 0; r < 4; ++r)
        XHb[(size_t)(rbase + i * 16 + r) * 256 + col] = f2bf(acc[i][j][r]);
    }
}

// ---- fused softmax + aggregation, half-wave row gathers (R7-best) -----------
__global__ __launch_bounds__(256) void gat_agg(
    const unsigned short* __restrict__ XHb, const float* __restrict__ a_src,
    const float* __restrict__ a_dst, const int* __restrict__ row_start,
    const int* __restrict__ csr_src, const float* __restrict__ bias,
    float* __restrict__ out, int N) {
  int wid = threadIdx.x >> 6;
  int lane = threadIdx.x & 63;
  int node = blockIdx.x * 4 + wid;
  if (node >= N) return;

  const int half = lane >> 5;
  const int l5 = lane & 31;
  const int h = l5 >> 3;
  const int c = l5 << 3;
  const unsigned short* __restrict__ xrow = XHb + c;

  float ad_h = a_dst[node * 4 + h];
  float as_h = a_src[node * 4 + h];

  int start = row_start[node];
  int end = row_start[node + 1];

  float acc[8];
  float sw = 0.f;
  if (half == 0) {
    float wself = __expf(LRELU(as_h + ad_h));
    ushort8 sv = *reinterpret_cast<const ushort8*>(xrow + (size_t)node * 256);
#pragma unroll
    for (int k = 0; k < 8; ++k) acc[k] = wself * bf2f(sv[k]);
    sw = wself;
  } else {
#pragma unroll
    for (int k = 0; k < 8; ++k) acc[k] = 0.f;
  }

  int p = start;
  for (; p + 8 <= end; p += 8) {
    int s0 = csr_src[p + half];
    int s1 = csr_src[p + 2 + half];
    int s2 = csr_src[p + 4 + half];
    int s3 = csr_src[p + 6 + half];
    float a0 = a_src[s0 * 4 + h] + ad_h;
    float a1 = a_src[s1 * 4 + h] + ad_h;
    float a2 = a_src[s2 * 4 + h] + ad_h;
    float a3 = a_src[s3 * 4 + h] + ad_h;
    ushort8 u0 = *reinterpret_cast<const ushort8*>(xrow + (size_t)s0 * 256);
    ushort8 u1 = *reinterpret_cast<const ushort8*>(xrow + (size_t)s1 * 256);
    ushort8 u2 = *reinterpret_cast<const ushort8*>(xrow + (size_t)s2 * 256);
    ushort8 u3 = *reinterpret_cast<const ushort8*>(xrow + (size_t)s3 * 256);
    float w0 = __expf(LRELU(a0));
    float w1 = __expf(LRELU(a1));
    float w2 = __expf(LRELU(a2));
    float w3 = __expf(LRELU(a3));
#pragma unroll
    for (int k = 0; k < 8; ++k) {
      acc[k] += w0 * bf2f(u0[k]);
      acc[k] += w1 * bf2f(u1[k]);
      acc[k] += w2 * bf2f(u2[k]);
      acc[k] += w3 * bf2f(u3[k]);
    }
    sw += (w0 + w1) + (w2 + w3);
  }
#pragma unroll
  for (int k = 0; k < 4; ++k) {
    int idx = p + 2 * k + half;
    if (idx < end) {
      int s = csr_src[idx];
      float aa = a_src[s * 4 + h] + ad_h;
      ushort8 u = *reinterpret_cast<const ushort8*>(xrow + (size_t)s * 256);
      float ww = __expf(LRELU(aa));
#pragma unroll
      for (int q = 0; q < 8; ++q) acc[q] += ww * bf2f(u[q]);
      sw += ww;
    }
  }

  sw += __shfl_xor(sw, 32, 64);
#pragma unroll
  for (int k = 0; k < 8; ++k) acc[k] += __shfl_xor(acc[k], 32, 64);

  if (half == 0) {
    float inv = 1.0f / sw;
    float4 b0 = *reinterpret_cast<const float4*>(bias + c);
    float4 b1 = *reinterpret_cast<const float4*>(bias + c + 4);
    float4 o0, o1;
    o0.x = acc[0] * inv + b0.x; o0.y = acc[1] * inv + b0.y;
    o0.z = acc[2] * inv + b0.z; o0.w = acc[3] * inv + b0.w;
    o1.x = acc[4] * inv + b1.x; o1.y = acc[5] * inv + b1.y;
    o1.z = acc[6] * inv + b1.z; o1.w = acc[7] * inv + b1.w;
    *reinterpret_cast<float4*>(out + (size_t)node * 256 + c) = o0;
    *reinterpret_cast<float4*>(out + (size_t)node * 256 + c + 4) = o1;
  }
}

extern "C" void kernel_launch(void* const* d_in, const int* in_sizes, int n_in,
                              void* d_out, int out_size, void* d_ws, size_t ws_size,
                              hipStream_t stream) {
  const float* x    = (const float*)d_in[0];
  const int*   ei   = (const int*)d_in[1];
  const float* Wm   = (const float*)d_in[2];
  const float* attS = (const float*)d_in[3];
  const float* attD = (const float*)d_in[4];
  const float* bias = (const float*)d_in[5];
  float* out = (float*)d_out;

  const int N = in_sizes[0] / 256;
  const int E = in_sizes[1] / 2;
  // m-block count must be a multiple of 8 for the XCD-paired gemm mapping
  // (R10 bug: 128-rounding gave 391 blocks -> truncated coverage + OOB writes)
  const int Mp = (N + 1023) / 1024 * 1024;
  const int nb = (N + 1023) / 1024;

  char* w = (char*)d_ws;
  unsigned short* XHb = (unsigned short*)w;  w += (size_t)Mp * 256 * 2;
  unsigned short* Wtb = (unsigned short*)w;  w += (size_t)256 * 256 * 2;
  float* a_src = (float*)w;                  w += (size_t)N * 4 * 4;
  float* a_dst = (float*)w;                  w += (size_t)N * 4 * 4;
  int* deg = (int*)w;                        w += (size_t)N * 4;
  int* next = (int*)w;                       w += (size_t)N * 4;
  int* row_start = (int*)w;                  w += ((size_t)(N + 1) * 4 + 255) / 256 * 256;
  int* bsum = (int*)w;                       w += ((size_t)nb * 4 + 255) / 256 * 256;
  int* csr_src = (int*)w;                    w += (size_t)E * 4;

  hipMemsetAsync(deg, 0, (size_t)N * 4, stream);

  fused_pre<<<CBC + CBW, 256, 0, stream>>>(Wm, Wtb, ei, deg, E);

  scan1_kernel<<<nb, 1024, 0, stream>>>(deg, row_start, bsum, N);
  scan_off<<<nb, 1024, 0, stream>>>(row_start, next, bsum, nb, N);

  const int nGemm = 2 * (Mp / 128);  // 784 = 49*16 at N=50000
  fused_main<<<CBF + nGemm, 256, 0, stream>>>(x, Wtb, attS, attD, XHb, a_src, a_dst,
                                              ei, next, csr_src, E, N);

  gat_agg<<<(N + 3) / 4, 256, 0, stream>>>(XHb, a_src, a_dst, row_start, csr_src,
                                           bias, out, N);
}

// Round 12
// 156.045 us; speedup vs baseline: 1.2745x; 1.2745x over previous
//
#include <hip/hip_runtime.h>

#define NEG_SLOPE 0.2f
#define LRELU(x) ((x) > 0.0f ? (x) : NEG_SLOPE * (x))

typedef short short8 __attribute__((ext_vector_type(8)));
typedef unsigned short ushort8 __attribute__((ext_vector_type(8)));
typedef float f32x4v __attribute__((ext_vector_type(4)));

__device__ __forceinline__ unsigned short f2bf(float f) {
  unsigned int u = __float_as_uint(f);
  unsigned int r = (u + 0x7FFFu + ((u >> 16) & 1u)) >> 16;
  return (unsigned short)r;
}

__device__ __forceinline__ float bf2f(unsigned short u) {
  return __uint_as_float(((unsigned int)u) << 16);
}

__device__ __forceinline__ unsigned int cvt_pk_bf16(float lo, float hi) {
  unsigned int r;
  asm("v_cvt_pk_bf16_f32 %0, %1, %2" : "=v"(r) : "v"(lo), "v"(hi));
  return r;
}

__device__ __forceinline__ void gload_lds16(const void* g, void* l) {
  __builtin_amdgcn_global_load_lds(
      (const __attribute__((address_space(1))) unsigned int*)g,
      (__attribute__((address_space(3))) unsigned int*)l, 16, 0, 0);
}

// block-range split constants
#define CBC 448    // count blocks (fused_pre)
#define CBW 64     // convert_wt blocks (fused_pre)
#define CBF 1024   // fill blocks (standalone)

// ---- K1: count+rank || convert_wt -------------------------------------------
// count phase stores the atomic's return value as the edge's within-node rank
// (coalesced write) -> the later fill needs NO atomics.
__global__ __launch_bounds__(256) void fused_pre(
    const float* __restrict__ W, unsigned short* __restrict__ Wtb,
    const int* __restrict__ ei, int* __restrict__ deg,
    int* __restrict__ rank, int E) {
  int b = blockIdx.x;
  int tid = threadIdx.x;
  if (b < CBC) {
    for (int e = b * 256 + tid; e < E; e += CBC * 256)
      rank[e] = atomicAdd(&deg[ei[E + e]], 1);
  } else {
    int bb = b - CBC;
    for (int idx = bb * 256 + tid; idx < 256 * 256; idx += CBW * 256) {
      int n = idx >> 8, k = idx & 255;
      Wtb[n * 256 + k] = f2bf(W[k * 256 + n]);
    }
  }
}

// ------------------------------- scan ----------------------------------------
__global__ __launch_bounds__(1024) void scan1_kernel(const int* __restrict__ deg,
                                                     int* __restrict__ row_start,
                                                     int* __restrict__ bsum, int N) {
  __shared__ int buf[1024];
  int i = blockIdx.x * 1024 + (int)threadIdx.x;
  int v = (i < N) ? deg[i] : 0;
  buf[threadIdx.x] = v;
  __syncthreads();
  int run = v;
  for (int off = 1; off < 1024; off <<= 1) {
    int t = ((int)threadIdx.x >= off) ? buf[threadIdx.x - off] : 0;
    __syncthreads();
    run += t;
    buf[threadIdx.x] = run;
    __syncthreads();
  }
  if (i < N) row_start[i] = run - v;  // exclusive, pre-block-offset
  if (threadIdx.x == 1023) bsum[blockIdx.x] = run;
}

__global__ __launch_bounds__(1024) void scan_off(int* __restrict__ row_start,
                                                 const int* __restrict__ bsum,
                                                 int nb, int N) {
  __shared__ int s_off;
  int b = blockIdx.x;
  if (threadIdx.x < 64) {
    int acc = 0;
    for (int j = (int)threadIdx.x; j < b; j += 64) acc += bsum[j];
    for (int off = 32; off; off >>= 1) acc += __shfl_down(acc, off, 64);
    if (threadIdx.x == 0) s_off = acc;
  }
  __syncthreads();
  int off = s_off;
  int i = b * 1024 + (int)threadIdx.x;
  if (i < N) row_start[i] += off;
  if (b == nb - 1 && threadIdx.x == 0) row_start[N] = off + bsum[b];
}

// ---- CSR fill, atomic-free: slot = row_start[d] + rank[e] -------------------
__global__ __launch_bounds__(256) void fill_kernel(
    const int* __restrict__ ei, const int* __restrict__ row_start,
    const int* __restrict__ rank, int* __restrict__ csr_src, int E) {
  for (int e = blockIdx.x * 256 + threadIdx.x; e < E; e += CBF * 256)
    csr_src[row_start[ei[E + e]] + rank[e]] = ei[e];
}

// ---- MFMA GEMM (128x128 tile, fused x->bf16 + att dots) ---------------------
// A: reg-staged f32 from X -> v_cvt_pk_bf16_f32 -> bf16 LDS. B: gload_lds.
// XCD-paired mapping (m-block count % 8 == 0 via Mp padded to 1024 rows).
__global__ __launch_bounds__(256) void gemm_mfma(
    const float* __restrict__ Xf, const unsigned short* __restrict__ Wtb,
    const float* __restrict__ attS, const float* __restrict__ attD,
    unsigned short* __restrict__ XHb, float* __restrict__ a_src,
    float* __restrict__ a_dst, int N) {
  __shared__ unsigned short lA[128 * 32];  // 8KB [row][k], 64B/row
  __shared__ unsigned short lB[128 * 32];  // 8KB [n][k],   64B/row
  const int gb = blockIdx.x;
  const int tid = threadIdx.x;
  const int lane = tid & 63;
  const int wave = tid >> 6;
  const int m0 = ((gb >> 4) * 8 + (gb & 7)) * 128;
  const int n0 = ((gb >> 3) & 1) * 128;
  const int wr = (wave >> 1) * 64;
  const int wc = (wave & 1) * 64;

  f32x4v acc[4][4];
#pragma unroll
  for (int i = 0; i < 4; ++i)
#pragma unroll
    for (int j = 0; j < 4; ++j) acc[i][j] = (f32x4v)(0.0f);

  const int srow = tid >> 2;
  const int skb = (tid & 3) * 16;
  const float* ap0 = Xf + (size_t)min(m0 + (tid >> 2), N - 1) * 256 + (tid & 3) * 8;
  const float* ap1 = Xf + (size_t)min(m0 + 64 + (tid >> 2), N - 1) * 256 + (tid & 3) * 8;

  const char* WtC = (const char*)Wtb;
  char* lAc = (char*)&lA[0];
  char* lBc = (char*)&lB[0];
  const int ldsB0 = wave * 1024;
  const int lr = lane & 15;
  const int hq = lane >> 4;
  const int kq = hq * 16;

  float4 c0 = *reinterpret_cast<const float4*>(ap0);
  float4 c1 = *reinterpret_cast<const float4*>(ap0 + 4);
  float4 c2 = *reinterpret_cast<const float4*>(ap1);
  float4 c3 = *reinterpret_cast<const float4*>(ap1 + 4);

#pragma unroll
  for (int kk = 0; kk < 8; ++kk) {
    const int k0 = kk * 32;
    gload_lds16(WtC + (size_t)(n0 + srow) * 512 + (size_t)k0 * 2 + skb, lBc + ldsB0);
    gload_lds16(WtC + (size_t)(n0 + srow + 64) * 512 + (size_t)k0 * 2 + skb,
                lBc + ldsB0 + 4096);
    {
      uint4 w0, w1;
      w0.x = cvt_pk_bf16(c0.x, c0.y); w0.y = cvt_pk_bf16(c0.z, c0.w);
      w0.z = cvt_pk_bf16(c1.x, c1.y); w0.w = cvt_pk_bf16(c1.z, c1.w);
      w1.x = cvt_pk_bf16(c2.x, c2.y); w1.y = cvt_pk_bf16(c2.z, c2.w);
      w1.z = cvt_pk_bf16(c3.x, c3.y); w1.w = cvt_pk_bf16(c3.z, c3.w);
      *reinterpret_cast<uint4*>(lAc + tid * 16) = w0;          // rows 0..63
      *reinterpret_cast<uint4*>(lAc + 4096 + tid * 16) = w1;   // rows 64..127
    }
    if (kk < 7) {
      c0 = *reinterpret_cast<const float4*>(ap0 + k0 + 32);
      c1 = *reinterpret_cast<const float4*>(ap0 + k0 + 36);
      c2 = *reinterpret_cast<const float4*>(ap1 + k0 + 32);
      c3 = *reinterpret_cast<const float4*>(ap1 + k0 + 36);
    }
    __syncthreads();

    short8 a[4], b[4];
#pragma unroll
    for (int i = 0; i < 4; ++i)
      a[i] = *reinterpret_cast<const short8*>(lAc + (wr + i * 16 + lr) * 64 + kq);
#pragma unroll
    for (int j = 0; j < 4; ++j)
      b[j] = *reinterpret_cast<const short8*>(lBc + (wc + j * 16 + lr) * 64 + kq);
#pragma unroll
    for (int i = 0; i < 4; ++i)
#pragma unroll
      for (int j = 0; j < 4; ++j)
        acc[i][j] = __builtin_amdgcn_mfma_f32_16x16x32_bf16(a[i], b[j], acc[i][j], 0, 0, 0);
    __syncthreads();
  }

  // ---- epilogue: fused attention dots + bf16 store ----
  const int h = (n0 + wc) >> 6;
  float ws_[4], wd_[4];
#pragma unroll
  for (int j = 0; j < 4; ++j) {
    ws_[j] = attS[h * 64 + j * 16 + lr];
    wd_[j] = attD[h * 64 + j * 16 + lr];
  }
  const int rbase = m0 + wr + hq * 4;

#pragma unroll
  for (int i = 0; i < 4; ++i) {
#pragma unroll
    for (int r = 0; r < 4; ++r) {
      float ps = 0.f, pd = 0.f;
#pragma unroll
      for (int j = 0; j < 4; ++j) {
        ps += acc[i][j][r] * ws_[j];
        pd += acc[i][j][r] * wd_[j];
      }
#pragma unroll
      for (int off = 1; off < 16; off <<= 1) {
        ps += __shfl_xor(ps, off, 64);
        pd += __shfl_xor(pd, off, 64);
      }
      int row = rbase + i * 16 + r;
      if (lr == 0 && row < N) {
        a_src[row * 4 + h] = ps;
        a_dst[row * 4 + h] = pd;
      }
    }
  }

#pragma unroll
  for (int i = 0; i < 4; ++i)
#pragma unroll
    for (int j = 0; j < 4; ++j) {
      int col = n0 + wc + j * 16 + lr;
#pragma unroll
      for (int r = 0; r < 4; ++r)
        XHb[(size_t)(rbase + i * 16 + r) * 256 + col] = f2bf(acc[i][j][r]);
    }
}

// ---- fused softmax + aggregation, half-wave row gathers (R7-best) -----------
__global__ __launch_bounds__(256) void gat_agg(
    const unsigned short* __restrict__ XHb, const float* __restrict__ a_src,
    const float* __restrict__ a_dst, const int* __restrict__ row_start,
    const int* __restrict__ csr_src, const float* __restrict__ bias,
    float* __restrict__ out, int N) {
  int wid = threadIdx.x >> 6;
  int lane = threadIdx.x & 63;
  int node = blockIdx.x * 4 + wid;
  if (node >= N) return;

  const int half = lane >> 5;
  const int l5 = lane & 31;
  const int h = l5 >> 3;
  const int c = l5 << 3;
  const unsigned short* __restrict__ xrow = XHb + c;

  float ad_h = a_dst[node * 4 + h];
  float as_h = a_src[node * 4 + h];

  int start = row_start[node];
  int end = row_start[node + 1];

  float acc[8];
  float sw = 0.f;
  if (half == 0) {
    float wself = __expf(LRELU(as_h + ad_h));
    ushort8 sv = *reinterpret_cast<const ushort8*>(xrow + (size_t)node * 256);
#pragma unroll
    for (int k = 0; k < 8; ++k) acc[k] = wself * bf2f(sv[k]);
    sw = wself;
  } else {
#pragma unroll
    for (int k = 0; k < 8; ++k) acc[k] = 0.f;
  }

  int p = start;
  for (; p + 8 <= end; p += 8) {
    int s0 = csr_src[p + half];
    int s1 = csr_src[p + 2 + half];
    int s2 = csr_src[p + 4 + half];
    int s3 = csr_src[p + 6 + half];
    float a0 = a_src[s0 * 4 + h] + ad_h;
    float a1 = a_src[s1 * 4 + h] + ad_h;
    float a2 = a_src[s2 * 4 + h] + ad_h;
    float a3 = a_src[s3 * 4 + h] + ad_h;
    ushort8 u0 = *reinterpret_cast<const ushort8*>(xrow + (size_t)s0 * 256);
    ushort8 u1 = *reinterpret_cast<const ushort8*>(xrow + (size_t)s1 * 256);
    ushort8 u2 = *reinterpret_cast<const ushort8*>(xrow + (size_t)s2 * 256);
    ushort8 u3 = *reinterpret_cast<const ushort8*>(xrow + (size_t)s3 * 256);
    float w0 = __expf(LRELU(a0));
    float w1 = __expf(LRELU(a1));
    float w2 = __expf(LRELU(a2));
    float w3 = __expf(LRELU(a3));
#pragma unroll
    for (int k = 0; k < 8; ++k) {
      acc[k] += w0 * bf2f(u0[k]);
      acc[k] += w1 * bf2f(u1[k]);
      acc[k] += w2 * bf2f(u2[k]);
      acc[k] += w3 * bf2f(u3[k]);
    }
    sw += (w0 + w1) + (w2 + w3);
  }
#pragma unroll
  for (int k = 0; k < 4; ++k) {
    int idx = p + 2 * k + half;
    if (idx < end) {
      int s = csr_src[idx];
      float aa = a_src[s * 4 + h] + ad_h;
      ushort8 u = *reinterpret_cast<const ushort8*>(xrow + (size_t)s * 256);
      float ww = __expf(LRELU(aa));
#pragma unroll
      for (int q = 0; q < 8; ++q) acc[q] += ww * bf2f(u[q]);
      sw += ww;
    }
  }

  sw += __shfl_xor(sw, 32, 64);
#pragma unroll
  for (int k = 0; k < 8; ++k) acc[k] += __shfl_xor(acc[k], 32, 64);

  if (half == 0) {
    float inv = 1.0f / sw;
    float4 b0 = *reinterpret_cast<const float4*>(bias + c);
    float4 b1 = *reinterpret_cast<const float4*>(bias + c + 4);
    float4 o0, o1;
    o0.x = acc[0] * inv + b0.x; o0.y = acc[1] * inv + b0.y;
    o0.z = acc[2] * inv + b0.z; o0.w = acc[3] * inv + b0.w;
    o1.x = acc[4] * inv + b1.x; o1.y = acc[5] * inv + b1.y;
    o1.z = acc[6] * inv + b1.z; o1.w = acc[7] * inv + b1.w;
    *reinterpret_cast<float4*>(out + (size_t)node * 256 + c) = o0;
    *reinterpret_cast<float4*>(out + (size_t)node * 256 + c + 4) = o1;
  }
}

extern "C" void kernel_launch(void* const* d_in, const int* in_sizes, int n_in,
                              void* d_out, int out_size, void* d_ws, size_t ws_size,
                              hipStream_t stream) {
  const float* x    = (const float*)d_in[0];
  const int*   ei   = (const int*)d_in[1];
  const float* Wm   = (const float*)d_in[2];
  const float* attS = (const float*)d_in[3];
  const float* attD = (const float*)d_in[4];
  const float* bias = (const float*)d_in[5];
  float* out = (float*)d_out;

  const int N = in_sizes[0] / 256;
  const int E = in_sizes[1] / 2;
  // m-block count must be a multiple of 8 for the XCD-paired gemm mapping
  const int Mp = (N + 1023) / 1024 * 1024;
  const int nb = (N + 1023) / 1024;

  char* w = (char*)d_ws;
  unsigned short* XHb = (unsigned short*)w;  w += (size_t)Mp * 256 * 2;
  unsigned short* Wtb = (unsigned short*)w;  w += (size_t)256 * 256 * 2;
  float* a_src = (float*)w;                  w += (size_t)N * 4 * 4;
  float* a_dst = (float*)w;                  w += (size_t)N * 4 * 4;
  int* deg = (int*)w;                        w += (size_t)N * 4;
  int* rank = (int*)w;                       w += (size_t)E * 4;
  int* row_start = (int*)w;                  w += ((size_t)(N + 1) * 4 + 255) / 256 * 256;
  int* bsum = (int*)w;                       w += ((size_t)nb * 4 + 255) / 256 * 256;
  int* csr_src = (int*)w;                    w += (size_t)E * 4;

  hipMemsetAsync(deg, 0, (size_t)N * 4, stream);

  // count (stores per-edge rank) || convert W
  fused_pre<<<CBC + CBW, 256, 0, stream>>>(Wm, Wtb, ei, deg, rank, E);

  scan1_kernel<<<nb, 1024, 0, stream>>>(deg, row_start, bsum, N);
  scan_off<<<nb, 1024, 0, stream>>>(row_start, bsum, nb, N);

  // GEMM (standalone for profile visibility)
  const int nGemm = 2 * (Mp / 128);
  gemm_mfma<<<nGemm, 256, 0, stream>>>(x, Wtb, attS, attD, XHb, a_src, a_dst, N);

  // atomic-free CSR fill
  fill_kernel<<<CBF, 256, 0, stream>>>(ei, row_start, rank, csr_src, E);

  gat_agg<<<(N + 3) / 4, 256, 0, stream>>>(XHb, a_src, a_dst, row_start, csr_src,
                                           bias, out, N);
}

// Round 13
// 148.708 us; speedup vs baseline: 1.3374x; 1.0493x over previous
//
#include <hip/hip_runtime.h>

#define NEG_SLOPE 0.2f
#define LRELU(x) ((x) > 0.0f ? (x) : NEG_SLOPE * (x))

typedef short short8 __attribute__((ext_vector_type(8)));
typedef unsigned short ushort8 __attribute__((ext_vector_type(8)));
typedef float f32x4v __attribute__((ext_vector_type(4)));

__device__ __forceinline__ unsigned short f2bf(float f) {
  unsigned int u = __float_as_uint(f);
  unsigned int r = (u + 0x7FFFu + ((u >> 16) & 1u)) >> 16;
  return (unsigned short)r;
}

__device__ __forceinline__ float bf2f(unsigned short u) {
  return __uint_as_float(((unsigned int)u) << 16);
}

__device__ __forceinline__ unsigned int cvt_pk_bf16(float lo, float hi) {
  unsigned int r;
  asm("v_cvt_pk_bf16_f32 %0, %1, %2" : "=v"(r) : "v"(lo), "v"(hi));
  return r;
}

__device__ __forceinline__ void gload_lds16(const void* g, void* l) {
  __builtin_amdgcn_global_load_lds(
      (const __attribute__((address_space(1))) unsigned int*)g,
      (__attribute__((address_space(3))) unsigned int*)l, 16, 0, 0);
}

// block-range split constants
#define CBC 448    // count blocks (fused_pre)
#define CBW 64     // convert_wt blocks (fused_pre)
#define CBF 1024   // fill blocks (fused_main, after gemm blocks)

// ---- K1: count+rank || convert_wt -------------------------------------------
// count stores the atomic's return value as the edge's within-node rank
// (coalesced write) -> fill needs NO atomics.
__global__ __launch_bounds__(256) void fused_pre(
    const float* __restrict__ W, unsigned short* __restrict__ Wtb,
    const int* __restrict__ ei, int* __restrict__ deg,
    int* __restrict__ rank, int E) {
  int b = blockIdx.x;
  int tid = threadIdx.x;
  if (b < CBC) {
    for (int e = b * 256 + tid; e < E; e += CBC * 256)
      rank[e] = atomicAdd(&deg[ei[E + e]], 1);
  } else {
    int bb = b - CBC;
    for (int idx = bb * 256 + tid; idx < 256 * 256; idx += CBW * 256) {
      int n = idx >> 8, k = idx & 255;
      Wtb[n * 256 + k] = f2bf(W[k * 256 + n]);
    }
  }
}

// ------------------------------- scan ----------------------------------------
__global__ __launch_bounds__(1024) void scan1_kernel(const int* __restrict__ deg,
                                                     int* __restrict__ row_start,
                                                     int* __restrict__ bsum, int N) {
  __shared__ int buf[1024];
  int i = blockIdx.x * 1024 + (int)threadIdx.x;
  int v = (i < N) ? deg[i] : 0;
  buf[threadIdx.x] = v;
  __syncthreads();
  int run = v;
  for (int off = 1; off < 1024; off <<= 1) {
    int t = ((int)threadIdx.x >= off) ? buf[threadIdx.x - off] : 0;
    __syncthreads();
    run += t;
    buf[threadIdx.x] = run;
    __syncthreads();
  }
  if (i < N) row_start[i] = run - v;  // exclusive, pre-block-offset
  if (threadIdx.x == 1023) bsum[blockIdx.x] = run;
}

__global__ __launch_bounds__(1024) void scan_off(int* __restrict__ row_start,
                                                 const int* __restrict__ bsum,
                                                 int nb, int N) {
  __shared__ int s_off;
  int b = blockIdx.x;
  if (threadIdx.x < 64) {
    int acc = 0;
    for (int j = (int)threadIdx.x; j < b; j += 64) acc += bsum[j];
    for (int off = 32; off; off >>= 1) acc += __shfl_down(acc, off, 64);
    if (threadIdx.x == 0) s_off = acc;
  }
  __syncthreads();
  int off = s_off;
  int i = b * 1024 + (int)threadIdx.x;
  if (i < N) row_start[i] += off;
  if (b == nb - 1 && threadIdx.x == 0) row_start[N] = off + bsum[b];
}

// ---- K4: MFMA GEMM (blocks [0,nGemm)) || atomic-free CSR fill ---------------
// gemm: 128x128 tile, reg-staged f32 A -> cvt_pk -> bf16 LDS; B via gload_lds;
// XCD-paired mapping (m-block count % 8 == 0 via Mp padded to 1024 rows).
// fill: csr_src[row_start[d] + rank[e]] = src[e]  (no atomics) — fill blocks
// backfill CUs as gemm blocks retire.
__global__ __launch_bounds__(256) void fused_main(
    const float* __restrict__ Xf, const unsigned short* __restrict__ Wtb,
    const float* __restrict__ attS, const float* __restrict__ attD,
    unsigned short* __restrict__ XHb, float* __restrict__ a_src,
    float* __restrict__ a_dst,
    const int* __restrict__ ei, const int* __restrict__ row_start,
    const int* __restrict__ rank, int* __restrict__ csr_src,
    int nGemm, int E, int N) {
  __shared__ unsigned short lA[128 * 32];  // 8KB [row][k], 64B/row
  __shared__ unsigned short lB[128 * 32];  // 8KB [n][k],   64B/row
  const int bid = blockIdx.x;
  const int tid = threadIdx.x;

  if (bid >= nGemm) {
    // ---------------- fill (atomic-free) ----------------
    int bb = bid - nGemm;
    for (int e = bb * 256 + tid; e < E; e += CBF * 256)
      csr_src[row_start[ei[E + e]] + rank[e]] = ei[e];
    return;
  }

  // ---------------- gemm ----------------
  const int gb = bid;
  const int lane = tid & 63;
  const int wave = tid >> 6;
  const int m0 = ((gb >> 4) * 8 + (gb & 7)) * 128;
  const int n0 = ((gb >> 3) & 1) * 128;
  const int wr = (wave >> 1) * 64;
  const int wc = (wave & 1) * 64;

  f32x4v acc[4][4];
#pragma unroll
  for (int i = 0; i < 4; ++i)
#pragma unroll
    for (int j = 0; j < 4; ++j) acc[i][j] = (f32x4v)(0.0f);

  const int srow = tid >> 2;
  const int skb = (tid & 3) * 16;
  const float* ap0 = Xf + (size_t)min(m0 + (tid >> 2), N - 1) * 256 + (tid & 3) * 8;
  const float* ap1 = Xf + (size_t)min(m0 + 64 + (tid >> 2), N - 1) * 256 + (tid & 3) * 8;

  const char* WtC = (const char*)Wtb;
  char* lAc = (char*)&lA[0];
  char* lBc = (char*)&lB[0];
  const int ldsB0 = wave * 1024;
  const int lr = lane & 15;
  const int hq = lane >> 4;
  const int kq = hq * 16;

  float4 c0 = *reinterpret_cast<const float4*>(ap0);
  float4 c1 = *reinterpret_cast<const float4*>(ap0 + 4);
  float4 c2 = *reinterpret_cast<const float4*>(ap1);
  float4 c3 = *reinterpret_cast<const float4*>(ap1 + 4);

#pragma unroll
  for (int kk = 0; kk < 8; ++kk) {
    const int k0 = kk * 32;
    gload_lds16(WtC + (size_t)(n0 + srow) * 512 + (size_t)k0 * 2 + skb, lBc + ldsB0);
    gload_lds16(WtC + (size_t)(n0 + srow + 64) * 512 + (size_t)k0 * 2 + skb,
                lBc + ldsB0 + 4096);
    {
      uint4 w0, w1;
      w0.x = cvt_pk_bf16(c0.x, c0.y); w0.y = cvt_pk_bf16(c0.z, c0.w);
      w0.z = cvt_pk_bf16(c1.x, c1.y); w0.w = cvt_pk_bf16(c1.z, c1.w);
      w1.x = cvt_pk_bf16(c2.x, c2.y); w1.y = cvt_pk_bf16(c2.z, c2.w);
      w1.z = cvt_pk_bf16(c3.x, c3.y); w1.w = cvt_pk_bf16(c3.z, c3.w);
      *reinterpret_cast<uint4*>(lAc + tid * 16) = w0;          // rows 0..63
      *reinterpret_cast<uint4*>(lAc + 4096 + tid * 16) = w1;   // rows 64..127
    }
    if (kk < 7) {
      c0 = *reinterpret_cast<const float4*>(ap0 + k0 + 32);
      c1 = *reinterpret_cast<const float4*>(ap0 + k0 + 36);
      c2 = *reinterpret_cast<const float4*>(ap1 + k0 + 32);
      c3 = *reinterpret_cast<const float4*>(ap1 + k0 + 36);
    }
    __syncthreads();

    short8 a[4], b[4];
#pragma unroll
    for (int i = 0; i < 4; ++i)
      a[i] = *reinterpret_cast<const short8*>(lAc + (wr + i * 16 + lr) * 64 + kq);
#pragma unroll
    for (int j = 0; j < 4; ++j)
      b[j] = *reinterpret_cast<const short8*>(lBc + (wc + j * 16 + lr) * 64 + kq);
#pragma unroll
    for (int i = 0; i < 4; ++i)
#pragma unroll
      for (int j = 0; j < 4; ++j)
        acc[i][j] = __builtin_amdgcn_mfma_f32_16x16x32_bf16(a[i], b[j], acc[i][j], 0, 0, 0);
    __syncthreads();
  }

  // ---- epilogue: fused attention dots + bf16 store ----
  const int h = (n0 + wc) >> 6;
  float ws_[4], wd_[4];
#pragma unroll
  for (int j = 0; j < 4; ++j) {
    ws_[j] = attS[h * 64 + j * 16 + lr];
    wd_[j] = attD[h * 64 + j * 16 + lr];
  }
  const int rbase = m0 + wr + hq * 4;

#pragma unroll
  for (int i = 0; i < 4; ++i) {
#pragma unroll
    for (int r = 0; r < 4; ++r) {
      float ps = 0.f, pd = 0.f;
#pragma unroll
      for (int j = 0; j < 4; ++j) {
        ps += acc[i][j][r] * ws_[j];
        pd += acc[i][j][r] * wd_[j];
      }
#pragma unroll
      for (int off = 1; off < 16; off <<= 1) {
        ps += __shfl_xor(ps, off, 64);
        pd += __shfl_xor(pd, off, 64);
      }
      int row = rbase + i * 16 + r;
      if (lr == 0 && row < N) {
        a_src[row * 4 + h] = ps;
        a_dst[row * 4 + h] = pd;
      }
    }
  }

#pragma unroll
  for (int i = 0; i < 4; ++i)
#pragma unroll
    for (int j = 0; j < 4; ++j) {
      int col = n0 + wc + j * 16 + lr;
#pragma unroll
      for (int r = 0; r < 4; ++r)
        XHb[(size_t)(rbase + i * 16 + r) * 256 + col] = f2bf(acc[i][j][r]);
    }
}

// ---- fused softmax + aggregation, half-wave row gathers (R7-best) -----------
__global__ __launch_bounds__(256) void gat_agg(
    const unsigned short* __restrict__ XHb, const float* __restrict__ a_src,
    const float* __restrict__ a_dst, const int* __restrict__ row_start,
    const int* __restrict__ csr_src, const float* __restrict__ bias,
    float* __restrict__ out, int N) {
  int wid = threadIdx.x >> 6;
  int lane = threadIdx.x & 63;
  int node = blockIdx.x * 4 + wid;
  if (node >= N) return;

  const int half = lane >> 5;
  const int l5 = lane & 31;
  const int h = l5 >> 3;
  const int c = l5 << 3;
  const unsigned short* __restrict__ xrow = XHb + c;

  float ad_h = a_dst[node * 4 + h];
  float as_h = a_src[node * 4 + h];

  int start = row_start[node];
  int end = row_start[node + 1];

  float acc[8];
  float sw = 0.f;
  if (half == 0) {
    float wself = __expf(LRELU(as_h + ad_h));
    ushort8 sv = *reinterpret_cast<const ushort8*>(xrow + (size_t)node * 256);
#pragma unroll
    for (int k = 0; k < 8; ++k) acc[k] = wself * bf2f(sv[k]);
    sw = wself;
  } else {
#pragma unroll
    for (int k = 0; k < 8; ++k) acc[k] = 0.f;
  }

  int p = start;
  for (; p + 8 <= end; p += 8) {
    int s0 = csr_src[p + half];
    int s1 = csr_src[p + 2 + half];
    int s2 = csr_src[p + 4 + half];
    int s3 = csr_src[p + 6 + half];
    float a0 = a_src[s0 * 4 + h] + ad_h;
    float a1 = a_src[s1 * 4 + h] + ad_h;
    float a2 = a_src[s2 * 4 + h] + ad_h;
    float a3 = a_src[s3 * 4 + h] + ad_h;
    ushort8 u0 = *reinterpret_cast<const ushort8*>(xrow + (size_t)s0 * 256);
    ushort8 u1 = *reinterpret_cast<const ushort8*>(xrow + (size_t)s1 * 256);
    ushort8 u2 = *reinterpret_cast<const ushort8*>(xrow + (size_t)s2 * 256);
    ushort8 u3 = *reinterpret_cast<const ushort8*>(xrow + (size_t)s3 * 256);
    float w0 = __expf(LRELU(a0));
    float w1 = __expf(LRELU(a1));
    float w2 = __expf(LRELU(a2));
    float w3 = __expf(LRELU(a3));
#pragma unroll
    for (int k = 0; k < 8; ++k) {
      acc[k] += w0 * bf2f(u0[k]);
      acc[k] += w1 * bf2f(u1[k]);
      acc[k] += w2 * bf2f(u2[k]);
      acc[k] += w3 * bf2f(u3[k]);
    }
    sw += (w0 + w1) + (w2 + w3);
  }
#pragma unroll
  for (int k = 0; k < 4; ++k) {
    int idx = p + 2 * k + half;
    if (idx < end) {
      int s = csr_src[idx];
      float aa = a_src[s * 4 + h] + ad_h;
      ushort8 u = *reinterpret_cast<const ushort8*>(xrow + (size_t)s * 256);
      float ww = __expf(LRELU(aa));
#pragma unroll
      for (int q = 0; q < 8; ++q) acc[q] += ww * bf2f(u[q]);
      sw += ww;
    }
  }

  sw += __shfl_xor(sw, 32, 64);
#pragma unroll
  for (int k = 0; k < 8; ++k) acc[k] += __shfl_xor(acc[k], 32, 64);

  if (half == 0) {
    float inv = 1.0f / sw;
    float4 b0 = *reinterpret_cast<const float4*>(bias + c);
    float4 b1 = *reinterpret_cast<const float4*>(bias + c + 4);
    float4 o0, o1;
    o0.x = acc[0] * inv + b0.x; o0.y = acc[1] * inv + b0.y;
    o0.z = acc[2] * inv + b0.z; o0.w = acc[3] * inv + b0.w;
    o1.x = acc[4] * inv + b1.x; o1.y = acc[5] * inv + b1.y;
    o1.z = acc[6] * inv + b1.z; o1.w = acc[7] * inv + b1.w;
    *reinterpret_cast<float4*>(out + (size_t)node * 256 + c) = o0;
    *reinterpret_cast<float4*>(out + (size_t)node * 256 + c + 4) = o1;
  }
}

extern "C" void kernel_launch(void* const* d_in, const int* in_sizes, int n_in,
                              void* d_out, int out_size, void* d_ws, size_t ws_size,
                              hipStream_t stream) {
  const float* x    = (const float*)d_in[0];
  const int*   ei   = (const int*)d_in[1];
  const float* Wm   = (const float*)d_in[2];
  const float* attS = (const float*)d_in[3];
  const float* attD = (const float*)d_in[4];
  const float* bias = (const float*)d_in[5];
  float* out = (float*)d_out;

  const int N = in_sizes[0] / 256;
  const int E = in_sizes[1] / 2;
  // m-block count must be a multiple of 8 for the XCD-paired gemm mapping
  const int Mp = (N + 1023) / 1024 * 1024;
  const int nb = (N + 1023) / 1024;

  char* w = (char*)d_ws;
  unsigned short* XHb = (unsigned short*)w;  w += (size_t)Mp * 256 * 2;
  unsigned short* Wtb = (unsigned short*)w;  w += (size_t)256 * 256 * 2;
  float* a_src = (float*)w;                  w += (size_t)N * 4 * 4;
  float* a_dst = (float*)w;                  w += (size_t)N * 4 * 4;
  int* deg = (int*)w;                        w += (size_t)N * 4;
  int* rank = (int*)w;                       w += (size_t)E * 4;
  int* row_start = (int*)w;                  w += ((size_t)(N + 1) * 4 + 255) / 256 * 256;
  int* bsum = (int*)w;                       w += ((size_t)nb * 4 + 255) / 256 * 256;
  int* csr_src = (int*)w;                    w += (size_t)E * 4;

  hipMemsetAsync(deg, 0, (size_t)N * 4, stream);

  // count (stores per-edge rank) || convert W
  fused_pre<<<CBC + CBW, 256, 0, stream>>>(Wm, Wtb, ei, deg, rank, E);

  scan1_kernel<<<nb, 1024, 0, stream>>>(deg, row_start, bsum, N);
  scan_off<<<nb, 1024, 0, stream>>>(row_start, bsum, nb, N);

  // GEMM || atomic-free fill (fill blocks backfill as gemm retires)
  const int nGemm = 2 * (Mp / 128);
  fused_main<<<nGemm + CBF, 256, 0, stream>>>(x, Wtb, attS, attD, XHb, a_src, a_dst,
                                              ei, row_start, rank, csr_src,
                                              nGemm, E, N);

  gat_agg<<<(N + 3) / 4, 256, 0, stream>>>(XHb, a_src, a_dst, row_start, csr_src,
                                           bias, out, N);
}